// Round 3
// baseline (1062.450 us; speedup 1.0000x reference)
//
#include <hip/hip_runtime.h>
#include <stdint.h>
#include <stddef.h>

// Problem constants (fixed by reference: B=8, T=4000)
#define NTOK   32000      // B*T
#define HID    1024
#define NQKV   3072
#define CTX    200
#define NH     16

typedef _Float16 f16;
typedef _Float16 f16x8 __attribute__((ext_vector_type(8)));
typedef _Float16 f16x4 __attribute__((ext_vector_type(4)));
typedef float    f32x4 __attribute__((ext_vector_type(4)));

__device__ __forceinline__ void async_copy16(const void* g, void* l) {
  typedef const __attribute__((address_space(1))) char gchar;
  typedef __attribute__((address_space(3))) char lchar;
  __builtin_amdgcn_global_load_lds((gchar*)g, (lchar*)l, 16, 0, 0);
}

// ---------------------------------------------------------------------------
// prep: wt_qkv[n][k] = [wq|wkv]^T as f16 ; wt_o[n][k] = wo^T ; rel -> f16
// ---------------------------------------------------------------------------
__global__ __launch_bounds__(256) void prep_kernel(
    const float* __restrict__ wq, const float* __restrict__ wkv,
    const float* __restrict__ wo, const float* __restrict__ rel,
    f16* __restrict__ wt_qkv, f16* __restrict__ wt_o, f16* __restrict__ rel_h) {
  long idx = (long)blockIdx.x * 256 + threadIdx.x;
  if (idx < (long)NQKV * HID) {
    int n = (int)(idx >> 10), k = (int)(idx & 1023);
    float v = (n < 1024) ? wq[(size_t)k * 1024 + n] : wkv[(size_t)k * 2048 + (n - 1024)];
    wt_qkv[idx] = (f16)v;
    return;
  }
  idx -= (long)NQKV * HID;
  if (idx < (long)HID * HID) {
    int n = (int)(idx >> 10), k = (int)(idx & 1023);
    wt_o[idx] = (f16)wo[(size_t)k * 1024 + n];
    return;
  }
  idx -= (long)HID * HID;
  if (idx < 1025 * 64) rel_h[idx] = (f16)rel[idx];
}

// ---------------------------------------------------------------------------
// LayerNorm: one block per token, 256 threads * float4, fp32 reduce -> f16 x
// ---------------------------------------------------------------------------
__global__ __launch_bounds__(256) void ln_kernel(
    const float* __restrict__ hs, const float* __restrict__ lw,
    const float* __restrict__ lb, f16* __restrict__ x) {
  int tok = blockIdx.x;
  int t = threadIdx.x;
  const float4* src = (const float4*)(hs + (size_t)tok * HID);
  float4 v = src[t];
  float s  = v.x + v.y + v.z + v.w;
  float s2 = v.x * v.x + v.y * v.y + v.z * v.z + v.w * v.w;
  for (int m = 1; m < 64; m <<= 1) { s += __shfl_xor(s, m); s2 += __shfl_xor(s2, m); }
  __shared__ float ps[4], ps2[4];
  int w = t >> 6;
  if ((t & 63) == 0) { ps[w] = s; ps2[w] = s2; }
  __syncthreads();
  s  = ps[0] + ps[1] + ps[2] + ps[3];
  s2 = ps2[0] + ps2[1] + ps2[2] + ps2[3];
  float mu  = s * (1.0f / 1024.0f);
  float var = s2 * (1.0f / 1024.0f) - mu * mu;
  float rs  = rsqrtf(var + 1e-5f);
  float4 wv = ((const float4*)lw)[t];
  float4 bv = ((const float4*)lb)[t];
  f16x4 o;
  o[0] = (f16)((v.x - mu) * rs * wv.x + bv.x);
  o[1] = (f16)((v.y - mu) * rs * wv.y + bv.y);
  o[2] = (f16)((v.z - mu) * rs * wv.z + bv.z);
  o[3] = (f16)((v.w - mu) * rs * wv.w + bv.w);
  *(f16x4*)(x + (size_t)tok * HID + t * 4) = o;
}

// ---------------------------------------------------------------------------
// GEMM: C[M,N] = A[M,1024] @ Bt[N,1024]^T, fp16 in / fp32 acc.
// 128x128 tile, BK=32, global_load_lds(16B), XOR-swizzled LDS.
// ---------------------------------------------------------------------------
template <int EPI>
__global__ __launch_bounds__(256) void gemm_kernel(
    const f16* __restrict__ A, const f16* __restrict__ Bt,
    void* __restrict__ C, const float* __restrict__ bias, int N) {
  __shared__ __attribute__((aligned(16))) f16 As[128 * 32];
  __shared__ __attribute__((aligned(16))) f16 Bs[128 * 32];
  int t = threadIdx.x;
  int w = t >> 6, l = t & 63;
  int m0 = blockIdx.y * 128;
  int n0 = blockIdx.x * 128;
  int wm = w >> 1, wn = w & 1;
  f32x4 acc[4][4] = {};
  int sr = t >> 2;   // staging row within 64-row half-tile
  int pg = t & 3;    // physical granule
  int lr = l & 15, lk = l >> 4;

  for (int k0 = 0; k0 < 1024; k0 += 32) {
    __syncthreads();
    #pragma unroll
    for (int c = 0; c < 2; ++c) {
      int r  = c * 64 + sr;
      int kg = pg ^ ((r >> 1) & 3);
      async_copy16(A  + (size_t)(m0 + r) * 1024 + k0 + kg * 8, (char*)As + c * 4096 + w * 1024);
      async_copy16(Bt + (size_t)(n0 + r) * 1024 + k0 + kg * 8, (char*)Bs + c * 4096 + w * 1024);
    }
    __syncthreads();
    f16x8 af[4], bf[4];
    #pragma unroll
    for (int mt = 0; mt < 4; ++mt) {
      int row = wm * 64 + mt * 16 + lr;
      int g = lk ^ ((row >> 1) & 3);
      af[mt] = *(const f16x8*)((const char*)As + row * 64 + g * 16);
    }
    #pragma unroll
    for (int nt = 0; nt < 4; ++nt) {
      int row = wn * 64 + nt * 16 + lr;
      int g = lk ^ ((row >> 1) & 3);
      bf[nt] = *(const f16x8*)((const char*)Bs + row * 64 + g * 16);
    }
    #pragma unroll
    for (int mt = 0; mt < 4; ++mt)
      #pragma unroll
      for (int nt = 0; nt < 4; ++nt)
        acc[mt][nt] = __builtin_amdgcn_mfma_f32_16x16x32_f16(af[mt], bf[nt], acc[mt][nt], 0, 0, 0);
  }

  #pragma unroll
  for (int mt = 0; mt < 4; ++mt)
    #pragma unroll
    for (int nt = 0; nt < 4; ++nt) {
      int gcol = n0 + wn * 64 + nt * 16 + lr;
      #pragma unroll
      for (int r = 0; r < 4; ++r) {
        int grow = m0 + wm * 64 + mt * 16 + lk * 4 + r;
        float v = acc[mt][nt][r];
        if constexpr (EPI == 0) {
          ((f16*)C)[(size_t)grow * N + gcol] = (f16)v;
        } else {
          ((float*)C)[(size_t)grow * N + gcol] = v + bias[gcol];
        }
      }
    }
}

// ---------------------------------------------------------------------------
// Block attention v2: one WG (4 waves) per (b, n, h) block-head.
// Barrier-free chunk loop: each wave owns whole 16-row chunks.
//   S (16x208) lives in registers (13 tiles, C-layout).
//   QK B-frags straight from global (L1-hot after chunk 0).
//   Rel bias: G[i,pp] = q_i . rel_emb[313+m0+pp], pp in [0,216) (14 tiles,
//   only the valid band) -> per-wave LDS buf -> reversed-contiguous gather
//   S[i,j] += G[i, i+199-j]. Softmax in registers (shfl over 16-lane groups).
//   P -> same LDS buf -> PV with Vt (6x K32 MFMA + 1x K16 tail MFMA).
// LDS: Vt 26,624 + 4x6,912 = 54,272 B -> 3 blocks/CU (12 waves, 37.5% occ).
// ---------------------------------------------------------------------------
__global__ __launch_bounds__(256, 3) void attn_kernel(
    const f16* __restrict__ qkv, const f16* __restrict__ rel_h,
    f16* __restrict__ out) {
  __shared__ __attribute__((aligned(16))) f16 Vt[64 * 208];      // 26,624 B
  __shared__ __attribute__((aligned(16))) f16 buf[4][16 * 216];  // 27,648 B

  int bh = blockIdx.x;
  int h  = bh & 15;
  int bn = bh >> 4;
  size_t t0 = (size_t)bn * CTX;
  int t = threadIdx.x;
  int w = t >> 6, l = t & 63;
  int lr = l & 15, lk = l >> 4;

  // ---- stage V transposed (vectorized writes), zero cols 200..207
  {
    int d = t & 63;
    const f16* vcol = qkv + t0 * NQKV + 2048 + h * 64 + d;
    for (int g = (t >> 6); g < 52; g += 4) {
      int j = g * 4;
      f16x4 pk;
      #pragma unroll
      for (int u = 0; u < 4; ++u) {
        int jj = j + u;
        pk[u] = (jj < 200) ? vcol[(size_t)jj * NQKV] : (f16)0.f;
      }
      *(f16x4*)(Vt + d * 208 + j) = pk;
    }
  }
  __syncthreads();

  const f16* qbase = qkv + t0 * NQKV + h * 64;
  const f16* kbase = qkv + t0 * NQKV + 1024 + h * 64;
  f16* bufw = buf[w];

  for (int c = w; c < 13; c += 4) {
    int m0 = c * 16;
    // ---- Q frags (global), pre-scaled by 1/sqrt(64)=0.125 (exact pow2)
    int qrow = m0 + lr; if (qrow > 199) qrow = 199;
    f16x8 aq0 = *(const f16x8*)(qbase + (size_t)qrow * NQKV + lk * 8);
    f16x8 aq1 = *(const f16x8*)(qbase + (size_t)qrow * NQKV + 32 + lk * 8);
    aq0 = aq0 * (f16)0.125f;
    aq1 = aq1 * (f16)0.125f;

    // ---- QK: 13 n-tiles, K rows from global
    f32x4 S[13];
    #pragma unroll
    for (int nt = 0; nt < 13; ++nt) {
      int krow = nt * 16 + lr; if (krow > 199) krow = 199;
      const f16* kr = kbase + (size_t)krow * NQKV;
      f16x8 b0 = *(const f16x8*)(kr + lk * 8);
      f16x8 b1 = *(const f16x8*)(kr + 32 + lk * 8);
      f32x4 a = {};
      a = __builtin_amdgcn_mfma_f32_16x16x32_f16(aq0, b0, a, 0, 0, 0);
      S[nt] = __builtin_amdgcn_mfma_f32_16x16x32_f16(aq1, b1, a, 0, 0, 0);
    }

    // ---- G: 14 tiles over valid band pp in [0,224), write masked pp<216
    const f16* rbase = rel_h + (size_t)(313 + m0) * 64;
    #pragma unroll
    for (int tg = 0; tg < 14; ++tg) {
      int pp = tg * 16 + lr;
      const f16* rr = rbase + (size_t)pp * 64;
      f16x8 b0 = *(const f16x8*)(rr + lk * 8);
      f16x8 b1 = *(const f16x8*)(rr + 32 + lk * 8);
      f32x4 a = {};
      a = __builtin_amdgcn_mfma_f32_16x16x32_f16(aq0, b0, a, 0, 0, 0);
      a = __builtin_amdgcn_mfma_f32_16x16x32_f16(aq1, b1, a, 0, 0, 0);
      if (pp < 216) {
        #pragma unroll
        for (int r = 0; r < 4; ++r)
          bufw[(lk * 4 + r) * 216 + pp] = (f16)a[r];
      }
    }

    // ---- gather rel bias: S[i, j] += G[i, i+199-j]   (reversed contiguous)
    #pragma unroll
    for (int r = 0; r < 4; ++r) {
      int i = lk * 4 + r;
      int base = i + 199 - lr;
      #pragma unroll
      for (int nt = 0; nt < 13; ++nt) {
        int pp = base - 16 * nt;
        if (pp < 0) pp = 0;  // only dead cols (j>=200) hit this
        S[nt][r] += (float)bufw[i * 216 + pp];
      }
    }
    // dead cols: tile 12, j = 192+lr >= 200 for lr >= 8
    if (lr >= 8) {
      #pragma unroll
      for (int r = 0; r < 4; ++r) S[12][r] = -1e30f;
    }

    // ---- softmax in registers (per row i = lk*4+r, reduce over 16 lanes)
    float inv[4];
    #pragma unroll
    for (int r = 0; r < 4; ++r) {
      float mx = S[0][r];
      #pragma unroll
      for (int nt = 1; nt < 13; ++nt) mx = fmaxf(mx, S[nt][r]);
      #pragma unroll
      for (int m = 1; m < 16; m <<= 1) mx = fmaxf(mx, __shfl_xor(mx, m));
      float sum = 0.f;
      #pragma unroll
      for (int nt = 0; nt < 13; ++nt) {
        float e = __expf(S[nt][r] - mx);
        S[nt][r] = e;
        sum += e;
      }
      #pragma unroll
      for (int m = 1; m < 16; m <<= 1) sum += __shfl_xor(sum, m);
      inv[r] = 1.0f / sum;
    }

    // ---- write P into bufw (overwrites G; same-wave ordering via lgkmcnt)
    #pragma unroll
    for (int nt = 0; nt < 13; ++nt)
      #pragma unroll
      for (int r = 0; r < 4; ++r)
        bufw[(lk * 4 + r) * 216 + nt * 16 + lr] = (f16)(S[nt][r] * inv[r]);
    // zero cols 200..207 (k-tail coverage)
    *(uint32_t*)(bufw + lr * 216 + 200 + lk * 2) = 0u;

    // ---- PV: O[16x64] = P[16x208] @ Vt^T, 6x K32 + 1x K16 tail
    f32x4 o[4] = {};
    #pragma unroll
    for (int ks = 0; ks < 6; ++ks) {
      f16x8 ap = *(const f16x8*)(bufw + lr * 216 + ks * 32 + lk * 8);
      #pragma unroll
      for (int dt = 0; dt < 4; ++dt) {
        f16x8 bv = *(const f16x8*)(Vt + (dt * 16 + lr) * 208 + ks * 32 + lk * 8);
        o[dt] = __builtin_amdgcn_mfma_f32_16x16x32_f16(ap, bv, o[dt], 0, 0, 0);
      }
    }
    {
      f16x4 ap = *(const f16x4*)(bufw + lr * 216 + 192 + lk * 4);
      #pragma unroll
      for (int dt = 0; dt < 4; ++dt) {
        f16x4 bv = *(const f16x4*)(Vt + (dt * 16 + lr) * 208 + 192 + lk * 4);
        o[dt] = __builtin_amdgcn_mfma_f32_16x16x16f16(ap, bv, o[dt], 0, 0, 0);
      }
    }

    // ---- store O chunk
    #pragma unroll
    for (int dt = 0; dt < 4; ++dt)
      #pragma unroll
      for (int r = 0; r < 4; ++r) {
        int i = lk * 4 + r;
        if (m0 + i < 200)
          out[(t0 + m0 + i) * HID + h * 64 + dt * 16 + lr] = (f16)o[dt][r];
      }
  }
}

// ---------------------------------------------------------------------------
extern "C" void kernel_launch(void* const* d_in, const int* in_sizes, int n_in,
                              void* d_out, int out_size, void* d_ws, size_t ws_size,
                              hipStream_t stream) {
  const float* hs  = (const float*)d_in[0];
  const float* lnw = (const float*)d_in[1];
  const float* lnb = (const float*)d_in[2];
  const float* wq  = (const float*)d_in[3];
  const float* wkv = (const float*)d_in[4];
  const float* wo  = (const float*)d_in[5];
  const float* bo  = (const float*)d_in[6];
  const float* rel = (const float*)d_in[7];

  // workspace layout (bytes); total ~271 MB
  char* ws = (char*)d_ws;
  f16* x     = (f16*)(ws);                         // 32000*1024*2 = 65,536,000
  f16* qkv   = (f16*)(ws + 65536000);              // 32000*3072*2 = 196,608,000
  f16* wtqkv = (f16*)(ws + 65536000 + 196608000);                  // 6,291,456
  f16* wto   = (f16*)(ws + 65536000 + 196608000 + 6291456);        // 2,097,152
  f16* rel_h = (f16*)(ws + 65536000 + 196608000 + 6291456 + 2097152); // 131,200
  f16* attn  = x;  // attention output aliases x (x dead after QKV GEMM)

  {
    long total = (long)NQKV * HID + (long)HID * HID + 1025 * 64;
    int grid = (int)((total + 255) / 256);
    prep_kernel<<<grid, 256, 0, stream>>>(wq, wkv, wo, rel, wtqkv, wto, rel_h);
  }
  ln_kernel<<<NTOK, 256, 0, stream>>>(hs, lnw, lnb, x);
  gemm_kernel<0><<<dim3(NQKV / 128, NTOK / 128), 256, 0, stream>>>(x, wtqkv, (void*)qkv, nullptr, NQKV);
  attn_kernel<<<2560, 256, 0, stream>>>(qkv, rel_h, attn);
  gemm_kernel<1><<<dim3(HID / 128, NTOK / 128), 256, 0, stream>>>(attn, wto, d_out, bo, HID);
}

// Round 4
// 760.631 us; speedup vs baseline: 1.3968x; 1.3968x over previous
//
#include <hip/hip_runtime.h>
#include <stdint.h>
#include <stddef.h>

// Problem constants (fixed by reference: B=8, T=4000)
#define NTOK   32000      // B*T
#define HID    1024
#define NQKV   3072
#define CTX    200
#define NH     16

typedef _Float16 f16;
typedef _Float16 f16x8 __attribute__((ext_vector_type(8)));
typedef _Float16 f16x4 __attribute__((ext_vector_type(4)));
typedef float    f32x4 __attribute__((ext_vector_type(4)));

__device__ __forceinline__ void async_copy16(const void* g, void* l) {
  typedef const __attribute__((address_space(1))) char gchar;
  typedef __attribute__((address_space(3))) char lchar;
  __builtin_amdgcn_global_load_lds((gchar*)g, (lchar*)l, 16, 0, 0);
}

// ---------------------------------------------------------------------------
// prep: wt_qkv[n][k] = [wq|wkv]^T as f16 ; wt_o[n][k] = wo^T ; rel -> f16
// ---------------------------------------------------------------------------
__global__ __launch_bounds__(256) void prep_kernel(
    const float* __restrict__ wq, const float* __restrict__ wkv,
    const float* __restrict__ wo, const float* __restrict__ rel,
    f16* __restrict__ wt_qkv, f16* __restrict__ wt_o, f16* __restrict__ rel_h) {
  long idx = (long)blockIdx.x * 256 + threadIdx.x;
  if (idx < (long)NQKV * HID) {
    int n = (int)(idx >> 10), k = (int)(idx & 1023);
    float v = (n < 1024) ? wq[(size_t)k * 1024 + n] : wkv[(size_t)k * 2048 + (n - 1024)];
    wt_qkv[idx] = (f16)v;
    return;
  }
  idx -= (long)NQKV * HID;
  if (idx < (long)HID * HID) {
    int n = (int)(idx >> 10), k = (int)(idx & 1023);
    wt_o[idx] = (f16)wo[(size_t)k * 1024 + n];
    return;
  }
  idx -= (long)HID * HID;
  if (idx < 1025 * 64) rel_h[idx] = (f16)rel[idx];
}

// ---------------------------------------------------------------------------
// LayerNorm: one block per token, 256 threads * float4, fp32 reduce -> f16 x
// ---------------------------------------------------------------------------
__global__ __launch_bounds__(256) void ln_kernel(
    const float* __restrict__ hs, const float* __restrict__ lw,
    const float* __restrict__ lb, f16* __restrict__ x) {
  int tok = blockIdx.x;
  int t = threadIdx.x;
  const float4* src = (const float4*)(hs + (size_t)tok * HID);
  float4 v = src[t];
  float s  = v.x + v.y + v.z + v.w;
  float s2 = v.x * v.x + v.y * v.y + v.z * v.z + v.w * v.w;
  for (int m = 1; m < 64; m <<= 1) { s += __shfl_xor(s, m); s2 += __shfl_xor(s2, m); }
  __shared__ float ps[4], ps2[4];
  int w = t >> 6;
  if ((t & 63) == 0) { ps[w] = s; ps2[w] = s2; }
  __syncthreads();
  s  = ps[0] + ps[1] + ps[2] + ps[3];
  s2 = ps2[0] + ps2[1] + ps2[2] + ps2[3];
  float mu  = s * (1.0f / 1024.0f);
  float var = s2 * (1.0f / 1024.0f) - mu * mu;
  float rs  = rsqrtf(var + 1e-5f);
  float4 wv = ((const float4*)lw)[t];
  float4 bv = ((const float4*)lb)[t];
  f16x4 o;
  o[0] = (f16)((v.x - mu) * rs * wv.x + bv.x);
  o[1] = (f16)((v.y - mu) * rs * wv.y + bv.y);
  o[2] = (f16)((v.z - mu) * rs * wv.z + bv.z);
  o[3] = (f16)((v.w - mu) * rs * wv.w + bv.w);
  *(f16x4*)(x + (size_t)tok * HID + t * 4) = o;
}

// ---------------------------------------------------------------------------
// GEMM: C[M,N] = A[M,1024] @ Bt[N,1024]^T, fp16 in / fp32 acc.
// 128x128 tile, BK=32, global_load_lds(16B), XOR-swizzled LDS.
// EPI==0: store f16 to BLOCKED qkv layout [bn][h][sel][200][64].
// EPI==1: store f32 + bias, row-major.
// ---------------------------------------------------------------------------
template <int EPI>
__global__ __launch_bounds__(256) void gemm_kernel(
    const f16* __restrict__ A, const f16* __restrict__ Bt,
    void* __restrict__ C, const float* __restrict__ bias, int N) {
  __shared__ __attribute__((aligned(16))) f16 As[128 * 32];
  __shared__ __attribute__((aligned(16))) f16 Bs[128 * 32];
  int t = threadIdx.x;
  int w = t >> 6, l = t & 63;
  int m0 = blockIdx.y * 128;
  int n0 = blockIdx.x * 128;
  int wm = w >> 1, wn = w & 1;
  f32x4 acc[4][4] = {};
  int sr = t >> 2;   // staging row within 64-row half-tile
  int pg = t & 3;    // physical granule
  int lr = l & 15, lk = l >> 4;

  for (int k0 = 0; k0 < 1024; k0 += 32) {
    __syncthreads();
    #pragma unroll
    for (int c = 0; c < 2; ++c) {
      int r  = c * 64 + sr;
      int kg = pg ^ ((r >> 1) & 3);
      async_copy16(A  + (size_t)(m0 + r) * 1024 + k0 + kg * 8, (char*)As + c * 4096 + w * 1024);
      async_copy16(Bt + (size_t)(n0 + r) * 1024 + k0 + kg * 8, (char*)Bs + c * 4096 + w * 1024);
    }
    __syncthreads();
    f16x8 af[4], bf[4];
    #pragma unroll
    for (int mt = 0; mt < 4; ++mt) {
      int row = wm * 64 + mt * 16 + lr;
      int g = lk ^ ((row >> 1) & 3);
      af[mt] = *(const f16x8*)((const char*)As + row * 64 + g * 16);
    }
    #pragma unroll
    for (int nt = 0; nt < 4; ++nt) {
      int row = wn * 64 + nt * 16 + lr;
      int g = lk ^ ((row >> 1) & 3);
      bf[nt] = *(const f16x8*)((const char*)Bs + row * 64 + g * 16);
    }
    #pragma unroll
    for (int mt = 0; mt < 4; ++mt)
      #pragma unroll
      for (int nt = 0; nt < 4; ++nt)
        acc[mt][nt] = __builtin_amdgcn_mfma_f32_16x16x32_f16(af[mt], bf[nt], acc[mt][nt], 0, 0, 0);
  }

  if constexpr (EPI == 0) {
    // blocked store: gcol -> (sel, h, d); grow -> (bn, io)
    #pragma unroll
    for (int mt = 0; mt < 4; ++mt) {
      #pragma unroll
      for (int r = 0; r < 4; ++r) {
        int grow = m0 + wm * 64 + mt * 16 + lk * 4 + r;
        unsigned bn = (unsigned)grow / 200u;
        unsigned io = (unsigned)grow - bn * 200u;
        #pragma unroll
        for (int nt = 0; nt < 4; ++nt) {
          int gcol = n0 + wn * 64 + nt * 16 + lr;
          int sel = gcol >> 10;
          int hh  = (gcol >> 6) & 15;
          int d   = gcol & 63;
          size_t addr = ((size_t)((bn * 16 + hh) * 3 + sel)) * 12800 + io * 64 + d;
          ((f16*)C)[addr] = (f16)acc[mt][nt][r];
        }
      }
    }
  } else {
    #pragma unroll
    for (int mt = 0; mt < 4; ++mt)
      #pragma unroll
      for (int nt = 0; nt < 4; ++nt) {
        int gcol = n0 + wn * 64 + nt * 16 + lr;
        #pragma unroll
        for (int r = 0; r < 4; ++r) {
          int grow = m0 + wm * 64 + mt * 16 + lk * 4 + r;
          ((float*)C)[(size_t)grow * N + gcol] = acc[mt][nt][r] + bias[gcol];
        }
      }
  }
}

// ---------------------------------------------------------------------------
// Block attention v3: one WG (4 waves) per (b, n, h); blocked qkv input.
// S^T = K.Q^T so softmaxed P lands in registers already in A-frag layout
// (K16 MFMA: k = 4*quad + reg) -> PV needs no LDS round trip for P.
//   - K staged once in LDS via global_load_lds, XOR-swizzled granules.
//   - V^T staged once in LDS [64][200].
//   - rel bias G^T[pp][i] = q_i . rel[313+m0+pp] via MFMA (rel rows from
//     global, L2-hot); through per-wave stride-17 LDS buf; gathered as
//     S^T[j][i] += G^T[i+199-j][i] (conflict-free scalar reads).
//   - O written via small LDS transpose -> full 128-B-line global stores.
// One barrier total; waves own whole 16-col chunks. LDS 81,464 B -> 2 WG/CU.
// ---------------------------------------------------------------------------
__global__ __launch_bounds__(256, 2) void attn_kernel(
    const f16* __restrict__ qkvb, const f16* __restrict__ rel_h,
    f16* __restrict__ out) {
  __shared__ __attribute__((aligned(16))) f16 Ks[208 * 64];     // 26,624 B
  __shared__ __attribute__((aligned(16))) f16 Vt[64 * 200];     // 25,600 B
  __shared__ __attribute__((aligned(16))) f16 Gb[4][215 * 17];  // 29,240 B

  int bh = blockIdx.x;
  int h  = bh & 15;
  size_t t0 = (size_t)(bh >> 4) * CTX;
  int t = threadIdx.x;
  int w = t >> 6, l = t & 63;
  int lr = l & 15, lk = l >> 4;

  const f16* Qb = qkvb + (size_t)bh * 38400;
  const f16* Kb = Qb + 12800;
  const f16* Vb = Qb + 25600;

  // ---- stage K, swizzled: phys granule pg holds logical pg ^ (row & 7)
  for (int it = w; it < 26; it += 4) {
    int srow = it * 8 + (l >> 3);
    int pg   = l & 7;
    int grow = srow < 200 ? srow : 199;   // pad rows: finite dup of row 199
    int gg   = pg ^ (srow & 7);
    async_copy16(Kb + (size_t)grow * 64 + gg * 8, (char*)Ks + it * 1024);
  }
  // ---- stage V^T: lane owns col d=l, wave handles j-quads w, w+4, ...
  {
    const f16* vcol = Vb + l;
    for (int g = w; g < 50; g += 4) {
      int j = g * 4;
      f16x4 pk;
      #pragma unroll
      for (int u = 0; u < 4; ++u) pk[u] = vcol[(size_t)(j + u) * 64];
      *(f16x4*)(Vt + l * 200 + j) = pk;
    }
  }
  __syncthreads();   // drains vmcnt (global_load_lds) + lgkm

  f16* gb = Gb[w];

  for (int c = w; c < 13; c += 4) {
    int m0 = c * 16;
    // ---- Q B-frags (pre-scaled by 1/8 = softmax scale, applies to QK & G)
    int qrow = m0 + lr; if (qrow > 199) qrow = 199;
    f16x8 bq0 = *(const f16x8*)(Qb + (size_t)qrow * 64 + lk * 8);
    f16x8 bq1 = *(const f16x8*)(Qb + (size_t)qrow * 64 + 32 + lk * 8);
    bq0 = bq0 * (f16)0.125f;
    bq1 = bq1 * (f16)0.125f;

    // ---- S^T[j][i]: A = K rows (LDS, swizzled), B = Q rows
    f32x4 S[13];
    #pragma unroll
    for (int ts = 0; ts < 13; ++ts) {
      int row = ts * 16 + lr;
      int sw  = row & 7;
      f16x8 a0 = *(const f16x8*)(Ks + row * 64 + (lk ^ sw) * 8);
      f16x8 a1 = *(const f16x8*)(Ks + row * 64 + ((4 + lk) ^ sw) * 8);
      f32x4 a = {};
      a = __builtin_amdgcn_mfma_f32_16x16x32_f16(a0, bq0, a, 0, 0, 0);
      S[ts] = __builtin_amdgcn_mfma_f32_16x16x32_f16(a1, bq1, a, 0, 0, 0);
    }

    // ---- G^T[pp][i]: A = rel rows (global, L2-hot), B = Q rows
    const f16* rb = rel_h + (size_t)(313 + m0) * 64;
    #pragma unroll
    for (int tg = 0; tg < 14; ++tg) {
      int pr = tg * 16 + lr;
      f16x8 a0 = *(const f16x8*)(rb + (size_t)pr * 64 + lk * 8);
      f16x8 a1 = *(const f16x8*)(rb + (size_t)pr * 64 + 32 + lk * 8);
      f32x4 g = {};
      g = __builtin_amdgcn_mfma_f32_16x16x32_f16(a0, bq0, g, 0, 0, 0);
      g = __builtin_amdgcn_mfma_f32_16x16x32_f16(a1, bq1, g, 0, 0, 0);
      #pragma unroll
      for (int r = 0; r < 4; ++r) {
        int pp2 = tg * 16 + 4 * lk + r;
        if (pp2 <= 214) gb[pp2 * 17 + lr] = (f16)g[r];
      }
    }

    // ---- gather: S^T[j][i] += G^T[i+199-j][i]
    #pragma unroll
    for (int ts = 0; ts < 13; ++ts) {
      #pragma unroll
      for (int r = 0; r < 4; ++r) {
        int pp = lr + 199 - ts * 16 - 4 * lk - r;
        if (pp < 0) pp = 0;   // only dead j (>=200) hit this
        S[ts][r] += (float)gb[pp * 17 + lr];
      }
    }
    // ---- mask dead j (tile 12, j = 192+4lk+r >= 200)
    #pragma unroll
    for (int r = 0; r < 4; ++r)
      if (4 * lk + r >= 8) S[12][r] = -1e30f;

    // ---- softmax over j (in-lane 52 values + lanes lr, lr+16, lr+32, lr+48)
    float mx = -1e30f;
    #pragma unroll
    for (int ts = 0; ts < 13; ++ts)
      #pragma unroll
      for (int r = 0; r < 4; ++r) mx = fmaxf(mx, S[ts][r]);
    mx = fmaxf(mx, __shfl_xor(mx, 16));
    mx = fmaxf(mx, __shfl_xor(mx, 32));
    float sum = 0.f;
    #pragma unroll
    for (int ts = 0; ts < 13; ++ts)
      #pragma unroll
      for (int r = 0; r < 4; ++r) {
        float e = __expf(S[ts][r] - mx);
        S[ts][r] = e;
        sum += e;
      }
    sum += __shfl_xor(sum, 16);
    sum += __shfl_xor(sum, 32);
    float inv = 1.0f / sum;

    // ---- P^T in registers == A-frags for K16 MFMA (k = 4*quad + reg)
    f16x4 P[13];
    #pragma unroll
    for (int ts = 0; ts < 13; ++ts)
      #pragma unroll
      for (int r = 0; r < 4; ++r) P[ts][r] = (f16)(S[ts][r] * inv);

    // ---- PV: D[i][d] = sum_j P[i][j] V^T[d][j], 4 d-tiles x 13 k-tiles
    f32x4 o[4] = {};
    #pragma unroll
    for (int ts = 0; ts < 13; ++ts) {
      int col4 = ts * 16 + 4 * lk;
      if (col4 > 196) col4 = 196;   // dead-k lanes only (P=0 there)
      #pragma unroll
      for (int dt = 0; dt < 4; ++dt) {
        f16x4 bv = *(const f16x4*)(Vt + (dt * 16 + lr) * 200 + col4);
        o[dt] = __builtin_amdgcn_mfma_f32_16x16x16f16(P[ts], bv, o[dt], 0, 0, 0);
      }
    }

    // ---- O via LDS transpose (reuse gb) -> full-line coalesced stores
    {
      f16* ob = gb;   // 16 x 72 f16 = 2304 B, fits in Gb[w]
      #pragma unroll
      for (int dt = 0; dt < 4; ++dt)
        #pragma unroll
        for (int r = 0; r < 4; ++r)
          ob[(4 * lk + r) * 72 + dt * 16 + lr] = (f16)o[dt][r];
      // read back row-major: lane l -> row l>>2, col quad (l&3)*16
      int orow = l >> 2;
      int ocol = (l & 3) * 16;
      if (m0 + orow < 200) {
        f16x8 v0 = *(const f16x8*)(ob + orow * 72 + ocol);
        f16x8 v1 = *(const f16x8*)(ob + orow * 72 + ocol + 8);
        f16* dst = out + (t0 + m0 + orow) * HID + h * 64 + ocol;
        *(f16x8*)dst = v0;
        *(f16x8*)(dst + 8) = v1;
      }
    }
  }
}

// ---------------------------------------------------------------------------
extern "C" void kernel_launch(void* const* d_in, const int* in_sizes, int n_in,
                              void* d_out, int out_size, void* d_ws, size_t ws_size,
                              hipStream_t stream) {
  const float* hs  = (const float*)d_in[0];
  const float* lnw = (const float*)d_in[1];
  const float* lnb = (const float*)d_in[2];
  const float* wq  = (const float*)d_in[3];
  const float* wkv = (const float*)d_in[4];
  const float* wo  = (const float*)d_in[5];
  const float* bo  = (const float*)d_in[6];
  const float* rel = (const float*)d_in[7];

  // workspace layout (bytes); total ~271 MB
  char* ws = (char*)d_ws;
  f16* x     = (f16*)(ws);                         // 32000*1024*2 = 65,536,000
  f16* qkvb  = (f16*)(ws + 65536000);              // 2560*38400*2 = 196,608,000
  f16* wtqkv = (f16*)(ws + 65536000 + 196608000);                  // 6,291,456
  f16* wto   = (f16*)(ws + 65536000 + 196608000 + 6291456);        // 2,097,152
  f16* rel_h = (f16*)(ws + 65536000 + 196608000 + 6291456 + 2097152); // 131,200
  f16* attn  = x;  // attention output aliases x (x dead after QKV GEMM)

  {
    long total = (long)NQKV * HID + (long)HID * HID + 1025 * 64;
    int grid = (int)((total + 255) / 256);
    prep_kernel<<<grid, 256, 0, stream>>>(wq, wkv, wo, rel, wtqkv, wto, rel_h);
  }
  ln_kernel<<<NTOK, 256, 0, stream>>>(hs, lnw, lnb, x);
  gemm_kernel<0><<<dim3(NQKV / 128, NTOK / 128), 256, 0, stream>>>(x, wtqkv, (void*)qkvb, nullptr, NQKV);
  attn_kernel<<<2560, 256, 0, stream>>>(qkvb, rel_h, attn);
  gemm_kernel<1><<<dim3(HID / 128, NTOK / 128), 256, 0, stream>>>(attn, wto, d_out, bo, HID);
}